// Round 7
// baseline (77.888 us; speedup 1.0000x reference)
//
#include <hip/hip_runtime.h>

// TemporalVoxelAttention — MFMA (bf16) fused.
// R7: 2 independent voxel-groups per wave (32 voxels/wave), weights/biases
// loaded ONCE per wave and shared by both groups (loop: {load B frag; MFMA g0;
// MFMA g1}). R6 evidence: latency-bound, per-wave latency inflates with
// occupancy (20us@6w -> 27us@9w per wave), nothing saturated -> TLP exhausted.
// ILP: two groups' chains interleave; ~60 weight loads + ~40 bias loads per
// wave now serve 2x work; wave count halves (6250->3128).
// Still fence-free (per-wave LDS ordering); 2x8KB disjoint slices per wave.
// d_ws holds weights pre-packed into MFMA B-fragment layout (94208 B).

using bf16x8 = __attribute__((ext_vector_type(8))) __bf16;
using f32x4  = __attribute__((ext_vector_type(4))) float;

#define DEV static __device__ __forceinline__

DEV float bf2f(unsigned short u){
  union { unsigned int i; float f; } v; v.i = ((unsigned int)u) << 16; return v.f;
}
DEV unsigned short f2bf(float f){
  union { float f; unsigned int i; } v; v.f = f;
  unsigned int x = v.i;
  x += 0x7FFFu + ((x >> 16) & 1u);           // RNE to bf16 (inputs finite)
  return (unsigned short)(x >> 16);
}

// LDS matrices: [rows][64] bf16 (128-B rows), XOR-swizzle byte ^= ((row&7)<<4).
DEV unsigned short* lp(unsigned short* base, int row, int col){
  int byte = (col << 1) ^ ((row & 7) << 4);
  return (unsigned short*)((char*)base + (row << 7) + byte);
}

// A-fragment: lane holds A[row = mt*16 + (lane&15)][k = kt*32 + (lane>>4)*8 + i]
DEV bf16x8 ldA(const unsigned short* base, int mt, int kt, int lane){
  int row = mt*16 + (lane & 15);
  int col = kt*32 + ((lane >> 4) << 3);
  return *(const bf16x8*)lp((unsigned short*)base, row, col);
}
// B-fragment: pre-packed in ws, lane-contiguous 16B
DEV bf16x8 ldB(const unsigned short* w, int frag, int lane){
  return *(const bf16x8*)(w + (size_t)frag*512 + (size_t)lane*8);
}
// C/D: col = lane&15, row = mt*16 + (lane>>4)*4 + r
DEV void stC(unsigned short* base, int mt, int nt, f32x4 c, int lane){
  int col  = nt*16 + (lane & 15);
  int row0 = mt*16 + ((lane >> 4) << 2);
  #pragma unroll
  for (int r = 0; r < 4; ++r) *lp(base, row0 + r, col) = f2bf(c[r]);
}
DEV f32x4 MF(bf16x8 a, bf16x8 b, f32x4 c){
  return __builtin_amdgcn_mfma_f32_16x16x32_bf16(a, b, c, 0, 0, 0);
}

DEV void ld16(const unsigned short* base, int row, int col0, float* o){
  uint4 a = *(const uint4*)lp((unsigned short*)base, row, col0);
  uint4 b = *(const uint4*)lp((unsigned short*)base, row, col0 + 8);
  unsigned int w[8] = {a.x, a.y, a.z, a.w, b.x, b.y, b.z, b.w};
  #pragma unroll
  for (int i = 0; i < 8; ++i){
    union { unsigned int u; float f; } lo, hi;
    lo.u = w[i] << 16; hi.u = w[i] & 0xFFFF0000u;
    o[2*i] = lo.f; o[2*i+1] = hi.f;
  }
}
DEV void st16(unsigned short* base, int row, int col0, const float* f){
  unsigned int w[8];
  #pragma unroll
  for (int i = 0; i < 8; ++i)
    w[i] = (unsigned int)f2bf(f[2*i]) | ((unsigned int)f2bf(f[2*i+1]) << 16);
  *(uint4*)lp(base, row, col0)     = make_uint4(w[0], w[1], w[2], w[3]);
  *(uint4*)lp(base, row, col0 + 8) = make_uint4(w[4], w[5], w[6], w[7]);
}

DEV bf16x8 pack8(const float* f){
  union { bf16x8 v; unsigned short u[8]; } r;
  #pragma unroll
  for (int i = 0; i < 8; ++i) r.u[i] = f2bf(f[i]);
  return r.v;
}

// LayerNorm over 64 cols for one 16-row M-tile held as 4 C-frags.
DEV void layer_norm16(f32x4 x[4], const float* g, const float* b, int lane){
  float s[4], s2[4];
  #pragma unroll
  for (int r = 0; r < 4; ++r){
    s[r]  = x[0][r] + x[1][r] + x[2][r] + x[3][r];
    s2[r] = x[0][r]*x[0][r] + x[1][r]*x[1][r] + x[2][r]*x[2][r] + x[3][r]*x[3][r];
  }
  #pragma unroll
  for (int o = 1; o <= 8; o <<= 1){
    #pragma unroll
    for (int r = 0; r < 4; ++r){
      s[r]  += __shfl_xor(s[r],  o);
      s2[r] += __shfl_xor(s2[r], o);
    }
  }
  float mu[4], rs[4];
  #pragma unroll
  for (int r = 0; r < 4; ++r){
    mu[r] = s[r] * (1.f/64.f);
    float var = s2[r] * (1.f/64.f) - mu[r]*mu[r];
    rs[r] = rsqrtf(var + 1e-5f);
  }
  const int cl = lane & 15;
  #pragma unroll
  for (int nt = 0; nt < 4; ++nt){
    float gg = g[nt*16 + cl], bb = b[nt*16 + cl];
    #pragma unroll
    for (int r = 0; r < 4; ++r)
      x[nt][r] = (x[nt][r] - mu[r]) * rs[r] * gg + bb;
  }
}

// ---------------- weight packing (unchanged) ----------------
// 0: pp_w1 (K=8 pad 32, N=64)   base 0,  4 frags
// 1: pp_w2 (K=64,  N=64)        base 4,  8
// 2: in_proj (K=64, N=192)      base 12, 24
// 3: out_w (K=64, N=64)         base 36, 8
// 4: ffn_w1 (K=64, N=128)       base 44, 16
// 5: ffn_w2 (K=128, N=64)       base 60, 16
// 6: op_w1 (K=64, N=64)         base 76, 8
// 7: op_w2 (K=64, N=64)         base 84, 8   -> 92 frags total
__global__ void tva_pack_weights(const float* __restrict__ pp_w1, const float* __restrict__ pp_w2,
                                 const float* __restrict__ in_proj_w, const float* __restrict__ out_w,
                                 const float* __restrict__ ffn_w1, const float* __restrict__ ffn_w2,
                                 const float* __restrict__ op_w1, const float* __restrict__ op_w2,
                                 unsigned short* __restrict__ ws)
{
  int b = blockIdx.x, lane = threadIdx.x;
  const float* W; int base, ktiles, K;
  if      (b < 4)  { W = pp_w1;     base = 0;  ktiles = 1; K = 8;   }
  else if (b < 12) { W = pp_w2;     base = 4;  ktiles = 2; K = 64;  }
  else if (b < 36) { W = in_proj_w; base = 12; ktiles = 2; K = 64;  }
  else if (b < 44) { W = out_w;     base = 36; ktiles = 2; K = 64;  }
  else if (b < 60) { W = ffn_w1;    base = 44; ktiles = 2; K = 64;  }
  else if (b < 76) { W = ffn_w2;    base = 60; ktiles = 4; K = 128; }
  else if (b < 84) { W = op_w1;     base = 76; ktiles = 2; K = 64;  }
  else             { W = op_w2;     base = 84; ktiles = 2; K = 64;  }
  int local = b - base;
  int nt = local / ktiles, kt = local % ktiles;
  int n  = nt*16 + (lane & 15);
  int k0 = kt*32 + ((lane >> 4) << 3);
  unsigned short* dst = ws + (size_t)b*512 + (size_t)lane*8;
  #pragma unroll
  for (int i = 0; i < 8; ++i){
    int k = k0 + i;
    float v = (k < K) ? W[(size_t)n*K + k] : 0.0f;
    dst[i] = f2bf(v);
  }
}

// ---------------- main kernel ----------------
__global__ __launch_bounds__(256)
void tva_main(const float* __restrict__ vf, const float* __restrict__ vox,
              const int* __restrict__ num_points,
              const float* __restrict__ pp_b1, const float* __restrict__ pp_b2,
              const float* __restrict__ ipb,  const float* __restrict__ outb,
              const float* __restrict__ ln1g, const float* __restrict__ ln1b,
              const float* __restrict__ f1b,  const float* __restrict__ f2bv,
              const float* __restrict__ ln2g, const float* __restrict__ ln2b,
              const float* __restrict__ o1b,  const float* __restrict__ o2b,
              const unsigned short* __restrict__ wfrag,
              float* __restrict__ out, int nvox)
{
  __shared__ unsigned short smem[4 * 2 * 64 * 64];   // 64 KB: 4 waves x 2 groups x 8 KB
  const int tid  = threadIdx.x;
  const int wv   = tid >> 6;
  const int lane = tid & 63;
  unsigned short* Xs[2] = { smem + wv*(2*64*64),             smem + wv*(2*64*64) + 64*64 };
  unsigned short* Qs[2] = { Xs[0] + 48*64,                   Xs[1] + 48*64 };

  const int v0 = (blockIdx.x * 4 + wv) * 32;   // 32 voxels per wave (2 groups x 16)
  if (v0 >= nvox) return;                      // tail waves idle (no barriers -> safe)
  const int cl = lane & 15;
  const int r0 = (lane >> 4) << 2;

  // ======== Phase A: point aggregation, both groups ========
  const int vi = lane >> 2, pq = lane & 3;
  bf16x8 ac[2], ah[2];
  unsigned int myfw[2];
  #pragma unroll
  for (int g = 0; g < 2; ++g){
    const int vg = v0 + g*16;
    const int np = num_points[vg + vi];
    float cs[8] = {0,0,0,0,0,0,0,0}, hs[8] = {0,0,0,0,0,0,0,0};
    float cc = 0.f, hc = 0.f;
    const float4* vp = (const float4*)(vox + (size_t)(vg + vi) * 384);
    #pragma unroll
    for (int k = 0; k < 12; ++k){
      int p = pq + (k << 2);
      float4 a = vp[p*2], b = vp[p*2 + 1];
      float pm = (p < np) ? 1.f : 0.f;
      float cm = (b.w > 0.5f) ? pm : 0.f;   // current: flag>0.5 & in-range
      float hm = pm - cm;                   // history: in-range & !current
      cc += cm; hc += hm;
      cs[0] += a.x*cm; cs[1] += a.y*cm; cs[2] += a.z*cm; cs[3] += a.w*cm;
      cs[4] += b.x*cm; cs[5] += b.y*cm; cs[6] += b.z*cm; cs[7] += b.w*cm;
      hs[0] += a.x*hm; hs[1] += a.y*hm; hs[2] += a.z*hm; hs[3] += a.w*hm;
      hs[4] += b.x*hm; hs[5] += b.y*hm; hs[6] += b.z*hm; hs[7] += b.w*hm;
    }
    #pragma unroll
    for (int o = 1; o <= 2; o <<= 1){
      cc += __shfl_xor(cc, o); hc += __shfl_xor(hc, o);
      #pragma unroll
      for (int j = 0; j < 8; ++j){
        cs[j] += __shfl_xor(cs[j], o);
        hs[j] += __shfl_xor(hs[j], o);
      }
    }
    const float icc = 1.f / fmaxf(cc, 1.f);
    const float ihc = 1.f / fmaxf(hc, 1.f);
    myfw[g] = (cc > 0.f ? 1u : 0u) | (hc > 0.f ? 2u : 0u);

    // Build pp-GEMM1 A-fragments in-register (16 shuffles; no LDS staging).
    const int src = cl * 4;   // any lane of voxel (lane&15) has the full sums
    float cf[8], hf[8];
    #pragma unroll
    for (int i = 0; i < 8; ++i){
      cf[i] = __shfl(cs[i]*icc, src);
      hf[i] = __shfl(hs[i]*ihc, src);
    }
    union { bf16x8 v; unsigned short u[8]; } rc, rh;
    #pragma unroll
    for (int i = 0; i < 8; ++i){
      rc.u[i] = (lane < 16) ? f2bf(cf[i]) : (unsigned short)0;
      rh.u[i] = (lane < 16) ? f2bf(hf[i]) : (unsigned short)0;
    }
    ac[g] = rc.v; ah[g] = rh.v;
  }

  // ======== Phase B: point_proj (8->64 relu, 64->64), B-frags shared ========
  #pragma unroll
  for (int nt = 0; nt < 4; ++nt){
    float bb = pp_b1[nt*16 + cl];
    bf16x8 B = ldB(wfrag, nt, lane);
    #pragma unroll
    for (int g = 0; g < 2; ++g){
      f32x4 c0 = {bb, bb, bb, bb}, c1 = {bb, bb, bb, bb};
      c0 = MF(ac[g], B, c0);
      c1 = MF(ah[g], B, c1);
      #pragma unroll
      for (int r = 0; r < 4; ++r){ c0[r] = fmaxf(c0[r], 0.f); c1[r] = fmaxf(c1[r], 0.f); }
      stC(Xs[g], 0, nt, c0, lane);   // hidden(cur) rows 0..15
      stC(Xs[g], 1, nt, c1, lane);   // hidden(his) rows 16..31
    }
  }
  {
    bf16x8 hfr[2][2][2];   // [g][m][kt]
    #pragma unroll
    for (int g = 0; g < 2; ++g)
      #pragma unroll
      for (int m = 0; m < 2; ++m)
        #pragma unroll
        for (int kt = 0; kt < 2; ++kt) hfr[g][m][kt] = ldA(Xs[g], m, kt, lane);
    // reads precede overwriting stores in program order (per-wave LDS order).
    #pragma unroll
    for (int nt = 0; nt < 4; ++nt){
      float bb = pp_b2[nt*16 + cl];
      bf16x8 B0 = ldB(wfrag, 4 + nt*2 + 0, lane);
      bf16x8 B1 = ldB(wfrag, 4 + nt*2 + 1, lane);
      #pragma unroll
      for (int g = 0; g < 2; ++g)
        #pragma unroll
        for (int m = 0; m < 2; ++m){
          f32x4 c = {bb, bb, bb, bb};
          c = MF(hfr[g][m][0], B0, c);
          c = MF(hfr[g][m][1], B1, c);
          stC(Xs[g], m, nt, c, lane);   // token1 rows 0..15, token2 rows 16..31
        }
    }
  }

  // ======== Phase C: QKV projections ========
  bf16x8 at[2][3][2];
  #pragma unroll
  for (int g = 0; g < 2; ++g){
    const float* s = vf + (size_t)(v0 + g*16 + cl) * 64 + ((lane >> 4) << 3);
    #pragma unroll
    for (int kt = 0; kt < 2; ++kt){
      float4 x0 = *(const float4*)(s + kt*32);
      float4 x1 = *(const float4*)(s + kt*32 + 4);
      float f[8] = {x0.x, x0.y, x0.z, x0.w, x1.x, x1.y, x1.z, x1.w};
      at[g][0][kt] = pack8(f);
    }
    #pragma unroll
    for (int kt = 0; kt < 2; ++kt){
      at[g][1][kt] = ldA(Xs[g], 0, kt, lane);
      at[g][2][kt] = ldA(Xs[g], 1, kt, lane);
    }
  }
  // q (token0 rows only), pre-scaled by 1/sqrt(DH)=0.25 -> Q
  #pragma unroll
  for (int nt = 0; nt < 4; ++nt){
    float bb = ipb[nt*16 + cl];
    bf16x8 B0 = ldB(wfrag, 12 + nt*2 + 0, lane);
    bf16x8 B1 = ldB(wfrag, 12 + nt*2 + 1, lane);
    #pragma unroll
    for (int g = 0; g < 2; ++g){
      f32x4 c = {bb, bb, bb, bb};
      c = MF(at[g][0][0], B0, c);
      c = MF(at[g][0][1], B1, c);
      #pragma unroll
      for (int r = 0; r < 4; ++r) c[r] *= 0.25f;
      stC(Qs[g], 0, nt, c, lane);
    }
  }
  // K (3 tokens) -> X rows 0..47
  #pragma unroll
  for (int nt = 0; nt < 4; ++nt){
    int ntg = 4 + nt;
    float bb = ipb[64 + nt*16 + cl];
    bf16x8 B0 = ldB(wfrag, 12 + ntg*2 + 0, lane);
    bf16x8 B1 = ldB(wfrag, 12 + ntg*2 + 1, lane);
    #pragma unroll
    for (int g = 0; g < 2; ++g)
      #pragma unroll
      for (int m = 0; m < 3; ++m){
        f32x4 c = {bb, bb, bb, bb};
        c = MF(at[g][m][0], B0, c);
        c = MF(at[g][m][1], B1, c);
        stC(Xs[g], m, nt, c, lane);
      }
  }

  // ======== Phase D1: scores + softmax (lane = (voxel, head)) ========
  const int av = cl, hh2 = lane >> 4;
  float p0[2], p1[2], p2[2];
  #pragma unroll
  for (int g = 0; g < 2; ++g){
    unsigned int fw = (unsigned int)__shfl((int)myfw[g], av*4);
    bool caZ = (fw & 1u) != 0, hpZ = (fw & 2u) != 0;
    float q[16]; ld16(Qs[g], av, hh2*16, q);
    float sc[3];
    #pragma unroll
    for (int m = 0; m < 3; ++m){
      float kv[16]; ld16(Xs[g], m*16 + av, hh2*16, kv);
      float d = 0.f;
      #pragma unroll
      for (int j = 0; j < 16; ++j) d += q[j]*kv[j];
      sc[m] = d;
    }
    float mx = sc[0];
    mx = caZ ? fmaxf(mx, sc[1]) : mx;
    mx = hpZ ? fmaxf(mx, sc[2]) : mx;
    float e0 = __expf(sc[0] - mx);
    float e1 = caZ ? __expf(sc[1] - mx) : 0.f;
    float e2 = hpZ ? __expf(sc[2] - mx) : 0.f;
    float inv = 1.f / (e0 + e1 + e2);
    p0[g] = e0*inv; p1[g] = e1*inv; p2[g] = e2*inv;
  }

  // ======== Phase C2: V projection -> X (K reads precede in program order) ========
  #pragma unroll
  for (int nt = 0; nt < 4; ++nt){
    int ntg = 8 + nt;
    float bb = ipb[128 + nt*16 + cl];
    bf16x8 B0 = ldB(wfrag, 12 + ntg*2 + 0, lane);
    bf16x8 B1 = ldB(wfrag, 12 + ntg*2 + 1, lane);
    #pragma unroll
    for (int g = 0; g < 2; ++g)
      #pragma unroll
      for (int m = 0; m < 3; ++m){
        f32x4 c = {bb, bb, bb, bb};
        c = MF(at[g][m][0], B0, c);
        c = MF(at[g][m][1], B1, c);
        stC(Xs[g], m, nt, c, lane);
      }
  }

  // ======== Phase D2: ctx = p . V  -> Q (overwrites q) ========
  #pragma unroll
  for (int g = 0; g < 2; ++g){
    float ctx[16];
    float vv[16];
    ld16(Xs[g], av, hh2*16, vv);
    #pragma unroll
    for (int j = 0; j < 16; ++j) ctx[j] = p0[g]*vv[j];
    ld16(Xs[g], 16 + av, hh2*16, vv);
    #pragma unroll
    for (int j = 0; j < 16; ++j) ctx[j] += p1[g]*vv[j];
    ld16(Xs[g], 32 + av, hh2*16, vv);
    #pragma unroll
    for (int j = 0; j < 16; ++j) ctx[j] += p2[g]*vv[j];
    st16(Qs[g], av, hh2*16, ctx);
  }

  // ======== Phase E: attn_out + residual + LN1 (token0 only) ========
  f32x4 res1[2][4];
  {
    bf16x8 a0[2], a1[2];
    #pragma unroll
    for (int g = 0; g < 2; ++g){ a0[g] = ldA(Qs[g], 0, 0, lane); a1[g] = ldA(Qs[g], 0, 1, lane); }
    #pragma unroll
    for (int nt = 0; nt < 4; ++nt){
      float bb = outb[nt*16 + cl];
      bf16x8 B0 = ldB(wfrag, 36 + nt*2 + 0, lane);
      bf16x8 B1 = ldB(wfrag, 36 + nt*2 + 1, lane);
      #pragma unroll
      for (int g = 0; g < 2; ++g){
        f32x4 c = {bb, bb, bb, bb};
        c = MF(a0[g], B0, c);
        c = MF(a1[g], B1, c);
        #pragma unroll
        for (int r = 0; r < 4; ++r)
          c[r] += vf[(size_t)(v0 + g*16 + r0 + r)*64 + nt*16 + cl];
        res1[g][nt] = c;
      }
    }
    #pragma unroll
    for (int g = 0; g < 2; ++g){
      layer_norm16(res1[g], ln1g, ln1b, lane);
      #pragma unroll
      for (int nt = 0; nt < 4; ++nt) stC(Qs[g], 0, nt, res1[g][nt], lane);
    }
  }

  // ======== Phase F: FFN (64->128 relu ->64) + residual + LN2 ========
  f32x4 tk2[2][4];
  {
    bf16x8 a0[2], a1[2], h0[2], h1[2];
    #pragma unroll
    for (int g = 0; g < 2; ++g){ a0[g] = ldA(Qs[g], 0, 0, lane); a1[g] = ldA(Qs[g], 0, 1, lane); }
    #pragma unroll
    for (int g = 0; g < 2; ++g)
      #pragma unroll
      for (int nt = 0; nt < 4; ++nt){
        float bb = f2bv[nt*16 + cl];
        tk2[g][nt] = (f32x4){bb, bb, bb, bb};
      }
    // h cols 0..63
    #pragma unroll
    for (int nt = 0; nt < 4; ++nt){
      float bb = f1b[nt*16 + cl];
      bf16x8 B0 = ldB(wfrag, 44 + nt*2 + 0, lane);
      bf16x8 B1 = ldB(wfrag, 44 + nt*2 + 1, lane);
      #pragma unroll
      for (int g = 0; g < 2; ++g){
        f32x4 c = {bb, bb, bb, bb};
        c = MF(a0[g], B0, c);
        c = MF(a1[g], B1, c);
        #pragma unroll
        for (int r = 0; r < 4; ++r) c[r] = fmaxf(c[r], 0.f);
        stC(Xs[g], 0, nt, c, lane);
      }
    }
    #pragma unroll
    for (int g = 0; g < 2; ++g){ h0[g] = ldA(Xs[g], 0, 0, lane); h1[g] = ldA(Xs[g], 0, 1, lane); }
    #pragma unroll
    for (int nt = 0; nt < 4; ++nt){
      bf16x8 B0 = ldB(wfrag, 60 + nt*4 + 0, lane);
      bf16x8 B1 = ldB(wfrag, 60 + nt*4 + 1, lane);
      #pragma unroll
      for (int g = 0; g < 2; ++g){
        tk2[g][nt] = MF(h0[g], B0, tk2[g][nt]);
        tk2[g][nt] = MF(h1[g], B1, tk2[g][nt]);
      }
    }
    // h cols 64..127 (h reads precede these stores in program order)
    #pragma unroll
    for (int nt = 4; nt < 8; ++nt){
      float bb = f1b[nt*16 + cl];
      bf16x8 B0 = ldB(wfrag, 44 + nt*2 + 0, lane);
      bf16x8 B1 = ldB(wfrag, 44 + nt*2 + 1, lane);
      #pragma unroll
      for (int g = 0; g < 2; ++g){
        f32x4 c = {bb, bb, bb, bb};
        c = MF(a0[g], B0, c);
        c = MF(a1[g], B1, c);
        #pragma unroll
        for (int r = 0; r < 4; ++r) c[r] = fmaxf(c[r], 0.f);
        stC(Xs[g], 0, nt - 4, c, lane);
      }
    }
    #pragma unroll
    for (int g = 0; g < 2; ++g){ h0[g] = ldA(Xs[g], 0, 0, lane); h1[g] = ldA(Xs[g], 0, 1, lane); }
    #pragma unroll
    for (int nt = 0; nt < 4; ++nt){
      bf16x8 B0 = ldB(wfrag, 60 + nt*4 + 2, lane);
      bf16x8 B1 = ldB(wfrag, 60 + nt*4 + 3, lane);
      #pragma unroll
      for (int g = 0; g < 2; ++g){
        tk2[g][nt] = MF(h0[g], B0, tk2[g][nt]);
        tk2[g][nt] = MF(h1[g], B1, tk2[g][nt]);
      }
    }
    #pragma unroll
    for (int g = 0; g < 2; ++g){
      #pragma unroll
      for (int nt = 0; nt < 4; ++nt)
        #pragma unroll
        for (int r = 0; r < 4; ++r) tk2[g][nt][r] += res1[g][nt][r];
      layer_norm16(tk2[g], ln2g, ln2b, lane);
      #pragma unroll
      for (int nt = 0; nt < 4; ++nt) stC(Qs[g], 0, nt, tk2[g][nt], lane);
    }
  }

  // ======== Phase G: output MLP + gate + final residual ========
  {
    bf16x8 a0[2], a1[2], b0[2], b1[2];
    #pragma unroll
    for (int g = 0; g < 2; ++g){ a0[g] = ldA(Qs[g], 0, 0, lane); a1[g] = ldA(Qs[g], 0, 1, lane); }
    #pragma unroll
    for (int nt = 0; nt < 4; ++nt){
      float bb = o1b[nt*16 + cl];
      bf16x8 B0 = ldB(wfrag, 76 + nt*2 + 0, lane);
      bf16x8 B1 = ldB(wfrag, 76 + nt*2 + 1, lane);
      #pragma unroll
      for (int g = 0; g < 2; ++g){
        f32x4 c = {bb, bb, bb, bb};
        c = MF(a0[g], B0, c);
        c = MF(a1[g], B1, c);
        #pragma unroll
        for (int r = 0; r < 4; ++r) c[r] = fmaxf(c[r], 0.f);
        stC(Xs[g], 0, nt, c, lane);
      }
    }
    #pragma unroll
    for (int g = 0; g < 2; ++g){ b0[g] = ldA(Xs[g], 0, 0, lane); b1[g] = ldA(Xs[g], 0, 1, lane); }
    #pragma unroll
    for (int nt = 0; nt < 4; ++nt){
      float bb = o2b[nt*16 + cl];
      bf16x8 B0 = ldB(wfrag, 84 + nt*2 + 0, lane);
      bf16x8 B1 = ldB(wfrag, 84 + nt*2 + 1, lane);
      #pragma unroll
      for (int g = 0; g < 2; ++g){
        f32x4 c = {bb, bb, bb, bb};
        c = MF(b0[g], B0, c);
        c = MF(b1[g], B1, c);
        #pragma unroll
        for (int r = 0; r < 4; ++r){
          int row = r0 + r;
          unsigned int fw2 = (unsigned int)__shfl((int)myfw[g], row*4);
          float keep = (fw2 & 2u) ? 1.f : 0.f;   // history_present gate
          size_t idx = (size_t)(v0 + g*16 + row)*64 + nt*16 + cl;
          out[idx] = vf[idx] + keep * c[r];
        }
      }
    }
  }
}

extern "C" void kernel_launch(void* const* d_in, const int* in_sizes, int n_in,
                              void* d_out, int out_size, void* d_ws, size_t ws_size,
                              hipStream_t stream)
{
  (void)n_in; (void)out_size; (void)ws_size;
  const float* vf    = (const float*)d_in[0];
  const float* vox   = (const float*)d_in[1];
  const float* pp_w1 = (const float*)d_in[2];
  const float* pp_b1 = (const float*)d_in[3];
  const float* pp_w2 = (const float*)d_in[4];
  const float* pp_b2 = (const float*)d_in[5];
  const float* ipw   = (const float*)d_in[6];
  const float* ipb   = (const float*)d_in[7];
  const float* outw  = (const float*)d_in[8];
  const float* outb  = (const float*)d_in[9];
  const float* ln1g  = (const float*)d_in[10];
  const float* ln1b  = (const float*)d_in[11];
  const float* f1w   = (const float*)d_in[12];
  const float* f1b   = (const float*)d_in[13];
  const float* f2w   = (const float*)d_in[14];
  const float* f2b   = (const float*)d_in[15];
  const float* ln2g  = (const float*)d_in[16];
  const float* ln2b  = (const float*)d_in[17];
  const float* o1w   = (const float*)d_in[18];
  const float* o1b   = (const float*)d_in[19];
  const float* o2w   = (const float*)d_in[20];
  const float* o2b   = (const float*)d_in[21];
  const int*   npts  = (const int*)d_in[22];
  unsigned short* wfrag = (unsigned short*)d_ws;   // 92*512*2 = 94208 B
  float* out = (float*)d_out;

  const int nvox  = in_sizes[0] / 64;        // 100000
  const int ndual = nvox / 32;               // 3125 dual-groups (32 voxels each)
  const int nblk  = (ndual + 3) / 4;         // 782 blocks x 4 waves
  tva_pack_weights<<<92, 64, 0, stream>>>(pp_w1, pp_w2, ipw, outw, f1w, f2w, o1w, o2w, wfrag);
  tva_main<<<nblk, 256, 0, stream>>>(vf, vox, npts, pp_b1, pp_b2, ipb, outb,
                                     ln1g, ln1b, f1b, f2b, ln2g, ln2b, o1b, o2b,
                                     wfrag, out, nvox);
}